// Round 3
// baseline (218.009 us; speedup 1.0000x reference)
//
#include <hip/hip_runtime.h>
#include <math.h>

#define D 64
#define C 22
#define NCHUNK 16
#define CHUNK 1024          // covers Nt=16384 exactly; INF-padded otherwise
#define SPT 2               // students per thread in nn role
#define TLP 24              // padded teacher-logit row (6 x float4)
#define TEMP_F 2.0f
#define KL_W_F 0.2f

// ================================================================ fat kernel
// blockIdx.x < nn_total  -> 1-NN role (chunked, 2 students/thread)
// else                   -> teacher-logits role (coalesced, no gather)
// tlogits is ~1 us of VALU work hidden under nn's ~25 us VALU-bound run.
__global__ void __launch_bounds__(256) fat_kernel(
        const float* __restrict__ sc,      // [Ns][3]
        const float* __restrict__ tc,      // [Nt][3]
        const float* __restrict__ t_feat,  // [Nt][D]
        const float* __restrict__ Wt,      // [C][D]
        const float* __restrict__ bt,      // [C]
        float2* __restrict__ cand,         // [NCHUNK][Ns]  (chunk-major!)
        float*  __restrict__ tlog,         // [Nt][TLP]
        float*  __restrict__ acc,          // [0]=seg [1]=kl
        unsigned* __restrict__ ct,         // finalize ticket
        int Ns, int Nt, int nn_total)
{
    __shared__ __align__(16) float smem[CHUNK * 4];   // 16 KiB, role-dependent use
    const int bx = blockIdx.x;

    if (bx == 0 && threadIdx.x == 0) { acc[0] = 0.f; acc[1] = 0.f; *ct = 0u; }

    if (bx < nn_total) {
        // ---------------- 1-NN role ----------------
        float4* tl = reinterpret_cast<float4*>(smem);
        const int chunk = bx & (NCHUNK - 1);
        const int sub   = bx >> 4;                     // log2(NCHUNK)
        const int base  = chunk * CHUNK;

        for (int j = threadIdx.x; j < CHUNK; j += blockDim.x) {
            int g = base + j;
            if (g < Nt) {
                float x = tc[(size_t)g * 3 + 0];
                float y = tc[(size_t)g * 3 + 1];
                float z = tc[(size_t)g * 3 + 2];
                tl[j] = make_float4(-2.f * x, -2.f * y, -2.f * z, x * x + y * y + z * z);
            } else {
                tl[j] = make_float4(0.f, 0.f, 0.f, INFINITY);
            }
        }
        __syncthreads();

        const int i0 = sub * (256 * SPT) + threadIdx.x;
        const int i1 = i0 + 256;

        float sx0 = 0.f, sy0 = 0.f, sz0 = 0.f, sx1 = 0.f, sy1 = 0.f, sz1 = 0.f;
        if (i0 < Ns) {
            sx0 = sc[(size_t)i0 * 3 + 0]; sy0 = sc[(size_t)i0 * 3 + 1]; sz0 = sc[(size_t)i0 * 3 + 2];
        }
        if (i1 < Ns) {
            sx1 = sc[(size_t)i1 * 3 + 0]; sy1 = sc[(size_t)i1 * 3 + 1]; sz1 = sc[(size_t)i1 * 3 + 2];
        }

        float best0 = INFINITY, best1 = INFINITY;
        int   b0 = base, b1 = base;
#pragma unroll 8
        for (int j = 0; j < CHUNK; ++j) {
            float4 t = tl[j];
            float v0 = fmaf(sx0, t.x, fmaf(sy0, t.y, fmaf(sz0, t.z, t.w)));
            float v1 = fmaf(sx1, t.x, fmaf(sy1, t.y, fmaf(sz1, t.z, t.w)));
            int jj = base + j;
            bool c0 = v0 < best0;                      // strict <: keep first min
            bool c1 = v1 < best1;
            best0 = c0 ? v0 : best0;  b0 = c0 ? jj : b0;
            best1 = c1 ? v1 : best1;  b1 = c1 ? jj : b1;
        }
        if (i0 < Ns) cand[(size_t)chunk * Ns + i0] = make_float2(best0, __int_as_float(b0));
        if (i1 < Ns) cand[(size_t)chunk * Ns + i1] = make_float2(best1, __int_as_float(b1));
    } else {
        // ---------------- teacher-logits role ----------------
        float* w = smem;                               // C*D floats
        float* b = smem + C * D;
        for (int k = threadIdx.x; k < C * D; k += blockDim.x) w[k] = Wt[k];
        if (threadIdx.x < C) b[threadIdx.x] = bt[threadIdx.x];
        __syncthreads();

        int i = (bx - nn_total) * 256 + threadIdx.x;
        if (i >= Nt) return;

        float4 f[D / 4];
        const float4* fr = reinterpret_cast<const float4*>(t_feat + (size_t)i * D);
#pragma unroll
        for (int k = 0; k < D / 4; ++k) f[k] = fr[k];

        float* row = tlog + (size_t)i * TLP;
#pragma unroll
        for (int c = 0; c < C; ++c) {
            float a = b[c];
            const float4* wr = reinterpret_cast<const float4*>(&w[c * D]);
#pragma unroll
            for (int k = 0; k < D / 4; ++k) {
                float4 wv = wr[k];
                a = fmaf(f[k].x, wv.x, a);
                a = fmaf(f[k].y, wv.y, a);
                a = fmaf(f[k].z, wv.z, a);
                a = fmaf(f[k].w, wv.w, a);
            }
            row[c] = a;
        }
        row[22] = 0.f;  row[23] = 0.f;                 // padding (loaded, never used)
    }
}

// ================================================================ loss (+finalize)
// 64-thread blocks (1 wave), 256 blocks -> every CU active. Coalesced cand
// reads (chunk-major float2), 96-B aligned logit gather, last-block finalize.
__global__ void __launch_bounds__(64) loss_kernel(
        const float* __restrict__ s_feat,   // [Ns][D]
        const float* __restrict__ Ws,       // [C][D]
        const float* __restrict__ bs_,      // [C]
        const int*   __restrict__ segment,  // [Ns]
        const float* __restrict__ tlog,     // [Nt][TLP]
        const float2* __restrict__ cand,    // [NCHUNK][Ns]
        float* __restrict__ acc,
        unsigned* __restrict__ ct,
        float* __restrict__ out,
        int Ns)
{
    __shared__ __align__(16) float ws[C * D];
    __shared__ float bsh[C];
    for (int k = threadIdx.x; k < C * D; k += blockDim.x) ws[k] = Ws[k];
    if (threadIdx.x < C) bsh[threadIdx.x] = bs_[threadIdx.x];
    __syncthreads();

    float seg_a = 0.f, kl_a = 0.f;

    for (int i = blockIdx.x * blockDim.x + threadIdx.x; i < Ns;
         i += gridDim.x * blockDim.x) {
        // ---- reduce NN candidates (k ascending, strict <: first occurrence)
        float2 c0 = cand[i];
        float best = c0.x;
        int   bidx = __float_as_int(c0.y);
#pragma unroll
        for (int k = 1; k < NCHUNK; ++k) {
            float2 cv = cand[(size_t)k * Ns + i];
            if (cv.x < best) { best = cv.x; bidx = __float_as_int(cv.y); }
        }

        // ---- gather matched teacher logits (6 x float4, 96 B aligned)
        float tt[TLP];
        {
            const float4* tr = reinterpret_cast<const float4*>(tlog + (size_t)bidx * TLP);
            float4* tp = reinterpret_cast<float4*>(tt);
#pragma unroll
            for (int k = 0; k < TLP / 4; ++k) tp[k] = tr[k];
        }

        // ---- student logits
        float l[C];
        {
            float4 f[D / 4];
            const float4* fr = reinterpret_cast<const float4*>(s_feat + (size_t)i * D);
#pragma unroll
            for (int k = 0; k < D / 4; ++k) f[k] = fr[k];
#pragma unroll
            for (int c = 0; c < C; ++c) {
                float a = bsh[c];
                const float4* wr = reinterpret_cast<const float4*>(&ws[c * D]);
#pragma unroll
                for (int k = 0; k < D / 4; ++k) {
                    float4 wv = wr[k];
                    a = fmaf(f[k].x, wv.x, a);
                    a = fmaf(f[k].y, wv.y, a);
                    a = fmaf(f[k].z, wv.z, a);
                    a = fmaf(f[k].w, wv.w, a);
                }
                l[c] = a;
            }
        }

        // ---- student softmax stats (T=1 for CE, T=2 for KL)
        float m1 = l[0];
#pragma unroll
        for (int c = 1; c < C; ++c) m1 = fmaxf(m1, l[c]);
        float sum1 = 0.f, sum2 = 0.f;
#pragma unroll
        for (int c = 0; c < C; ++c) {
            float d = l[c] - m1;
            sum1 += expf(d);
            sum2 += expf(0.5f * d);
        }
        float lse1 = logf(sum1);
        float lse2 = logf(sum2);

        int sg = segment[i];
        seg_a += -(l[sg] - m1 - lse1);

        // ---- teacher softmax (T=2) + KL
        float mt = tt[0];
#pragma unroll
        for (int c = 1; c < C; ++c) mt = fmaxf(mt, tt[c]);
        float den = 0.f;
        float e[C];
#pragma unroll
        for (int c = 0; c < C; ++c) {
            e[c] = expf(0.5f * (tt[c] - mt));
            den += e[c];
        }
        float logden = logf(den);
        float inv = 1.0f / den;

        float kls = 0.f;
#pragma unroll
        for (int c = 0; c < C; ++c) {
            float logtp = 0.5f * (tt[c] - mt) - logden;   // log teacher_p
            float slp   = 0.5f * (l[c] - m1) - lse2;      // student log-softmax (T=2)
            kls = fmaf(e[c] * inv, logtp - slp, kls);
        }
        kl_a += kls;
    }

    // ---- single-wave shuffle reduce, one atomic pair per block
#pragma unroll
    for (int off = 32; off > 0; off >>= 1) {
        seg_a += __shfl_down(seg_a, off);
        kl_a  += __shfl_down(kl_a,  off);
    }
    if (threadIdx.x == 0) {
        atomicAdd(&acc[0], seg_a);
        atomicAdd(&acc[1], kl_a);
        __threadfence();
        unsigned t = atomicAdd(ct, 1u);
        if (t == gridDim.x - 1) {
            float seg = atomicAdd(&acc[0], 0.f);   // L2-coherent read
            float kl  = atomicAdd(&acc[1], 0.f);
            float seg_loss = seg / (float)Ns;
            float kl_loss  = KL_W_F * (kl / (float)Ns) * TEMP_F * TEMP_F;
            out[0] = seg_loss + kl_loss;
            out[1] = seg_loss;
            out[2] = kl_loss;
        }
    }
}

extern "C" void kernel_launch(void* const* d_in, const int* in_sizes, int n_in,
                              void* d_out, int out_size, void* d_ws, size_t ws_size,
                              hipStream_t stream)
{
    const float* s_feat  = (const float*)d_in[0];
    const float* t_feat  = (const float*)d_in[1];
    const float* s_coord = (const float*)d_in[2];
    const float* t_coord = (const float*)d_in[3];
    const float* seg_W   = (const float*)d_in[4];
    const float* seg_b   = (const float*)d_in[5];
    const float* seg_tW  = (const float*)d_in[6];
    const float* seg_tb  = (const float*)d_in[7];
    const int*   segment = (const int*)d_in[8];
    float* out = (float*)d_out;

    const int Ns = in_sizes[0] / D;
    const int Nt = in_sizes[1] / D;

    float*  tlog = (float*)d_ws;                                   // [Nt*TLP]
    float2* cand = (float2*)(tlog + (size_t)Nt * TLP);             // [NCHUNK*Ns]
    float*  acc  = (float*)(cand + (size_t)NCHUNK * Ns);           // [2]
    unsigned* ct = (unsigned*)(acc + 2);

    const int nn_bx    = (Ns + 256 * SPT - 1) / (256 * SPT);       // 32
    const int nn_total = nn_bx * NCHUNK;                           // 512
    const int ntb      = (Nt + 255) / 256;                         // 64

    fat_kernel<<<nn_total + ntb, 256, 0, stream>>>(
        s_coord, t_coord, t_feat, seg_tW, seg_tb,
        cand, tlog, acc, ct, Ns, Nt, nn_total);

    loss_kernel<<<256, 64, 0, stream>>>(
        s_feat, seg_W, seg_b, segment, tlog, cand, acc, ct, out, Ns);
}

// Round 4
// 131.240 us; speedup vs baseline: 1.6611x; 1.6611x over previous
//
#include <hip/hip_runtime.h>
#include <math.h>

#define D 64
#define C 22
#define NCHUNK 32
#define CHUNK 512           // NCHUNK*CHUNK covers Nt=16384; INF-padded otherwise
#define SPT 4               // students per thread in nn role
#define TLP 24              // padded teacher-logit row (6 x float4)
#define TEMP_F 2.0f
#define KL_W_F 0.2f

// ================================================================ fat kernel
// blockIdx.x < nn_total  -> 1-NN role (chunked, 4 students/thread)
// else                   -> teacher-logits role (coalesced, no gather)
__global__ void __launch_bounds__(256) fat_kernel(
        const float* __restrict__ sc,      // [Ns][3]
        const float* __restrict__ tc,      // [Nt][3]
        const float* __restrict__ t_feat,  // [Nt][D]
        const float* __restrict__ Wt,      // [C][D]
        const float* __restrict__ bt,      // [C]
        float*  __restrict__ cand_d,       // [NCHUNK][Ns]  chunk-major
        unsigned short* __restrict__ cand_j, // [NCHUNK][Ns] within-chunk argmin
        float*  __restrict__ tlog,         // [Nt][TLP]
        float*  __restrict__ acc,          // [0]=seg [1]=kl
        unsigned* __restrict__ ct,         // finalize ticket
        int Ns, int Nt, int nn_total)
{
    __shared__ __align__(16) float smem[CHUNK * 4];   // 8 KiB, role-dependent
    const int bx = blockIdx.x;

    if (bx == 0 && threadIdx.x == 0) { acc[0] = 0.f; acc[1] = 0.f; *ct = 0u; }

    if (bx < nn_total) {
        // ---------------- 1-NN role ----------------
        float4* tl = reinterpret_cast<float4*>(smem);
        const int chunk = bx & (NCHUNK - 1);
        const int sub   = bx >> 5;                     // log2(NCHUNK)
        const int base  = chunk * CHUNK;

        for (int j = threadIdx.x; j < CHUNK; j += 256) {
            int g = base + j;
            if (g < Nt) {
                float x = tc[(size_t)g * 3 + 0];
                float y = tc[(size_t)g * 3 + 1];
                float z = tc[(size_t)g * 3 + 2];
                tl[j] = make_float4(-2.f * x, -2.f * y, -2.f * z, x * x + y * y + z * z);
            } else {
                tl[j] = make_float4(0.f, 0.f, 0.f, INFINITY);
            }
        }
        __syncthreads();

        const int i0 = sub * (256 * SPT) + threadIdx.x;
        float sx[SPT], sy[SPT], sz[SPT];
#pragma unroll
        for (int s = 0; s < SPT; ++s) {
            int i = i0 + s * 256;
            sx[s] = 0.f; sy[s] = 0.f; sz[s] = 0.f;
            if (i < Ns) {
                sx[s] = sc[(size_t)i * 3 + 0];
                sy[s] = sc[(size_t)i * 3 + 1];
                sz[s] = sc[(size_t)i * 3 + 2];
            }
        }
        float best[SPT]; int bj[SPT];
#pragma unroll
        for (int s = 0; s < SPT; ++s) { best[s] = INFINITY; bj[s] = 0; }

#pragma unroll 8
        for (int j = 0; j < CHUNK; ++j) {
            float4 t = tl[j];
#pragma unroll
            for (int s = 0; s < SPT; ++s) {
                // |t|^2 - 2 s.t  (|s|^2 constant per student: same argmin)
                float v = fmaf(sx[s], t.x, fmaf(sy[s], t.y, fmaf(sz[s], t.z, t.w)));
                bool c = v < best[s];                  // strict <: first-min
                best[s] = c ? v : best[s];
                bj[s]   = c ? j : bj[s];
            }
        }
#pragma unroll
        for (int s = 0; s < SPT; ++s) {
            int i = i0 + s * 256;
            if (i < Ns) {
                cand_d[(size_t)chunk * Ns + i] = best[s];
                cand_j[(size_t)chunk * Ns + i] = (unsigned short)bj[s];
            }
        }
    } else {
        // ---------------- teacher-logits role ----------------
        float* w = smem;                               // C*D floats
        float* b = smem + C * D;
        for (int k = threadIdx.x; k < C * D; k += 256) w[k] = Wt[k];
        if (threadIdx.x < C) b[threadIdx.x] = bt[threadIdx.x];
        __syncthreads();

        int i = (bx - nn_total) * 256 + threadIdx.x;
        if (i >= Nt) return;

        float4 f[D / 4];
        const float4* fr = reinterpret_cast<const float4*>(t_feat + (size_t)i * D);
#pragma unroll
        for (int k = 0; k < D / 4; ++k) f[k] = fr[k];

        float* row = tlog + (size_t)i * TLP;
#pragma unroll
        for (int c = 0; c < C; ++c) {
            float a = b[c];
            const float4* wr = reinterpret_cast<const float4*>(&w[c * D]);
#pragma unroll
            for (int k = 0; k < D / 4; ++k) {
                float4 wv = wr[k];
                a = fmaf(f[k].x, wv.x, a);
                a = fmaf(f[k].y, wv.y, a);
                a = fmaf(f[k].z, wv.z, a);
                a = fmaf(f[k].w, wv.w, a);
            }
            row[c] = a;
        }
        row[22] = 0.f;  row[23] = 0.f;                 // padding
    }
}

// ================================================================ loss (+finalize)
// Low-pressure design: only f[16xfloat4] + tt[24] + 6 scalars live.
// Student logits recomputed in pass B (1408 extra FMA/row << spill cost).
__global__ void __launch_bounds__(128) loss_kernel(
        const float* __restrict__ s_feat,   // [Ns][D]
        const float* __restrict__ Ws,       // [C][D]
        const float* __restrict__ bs_,      // [C]
        const int*   __restrict__ segment,  // [Ns]
        const float* __restrict__ tlog,     // [Nt][TLP]
        const float* __restrict__ cand_d,   // [NCHUNK][Ns]
        const unsigned short* __restrict__ cand_j,
        float* __restrict__ acc,
        unsigned* __restrict__ ct,
        float* __restrict__ out,
        int Ns)
{
    __shared__ __align__(16) float ws[C * D];
    __shared__ float bsh[C];
    __shared__ float rs[2], rk[2];
    for (int k = threadIdx.x; k < C * D; k += blockDim.x) ws[k] = Ws[k];
    if (threadIdx.x < C) bsh[threadIdx.x] = bs_[threadIdx.x];
    __syncthreads();

    float seg_a = 0.f, kl_a = 0.f;

    for (int i = blockIdx.x * blockDim.x + threadIdx.x; i < Ns;
         i += gridDim.x * blockDim.x) {
        // ---- reduce chunk minima (k ascending, strict <: first occurrence)
        float best = cand_d[i];
        int bk = 0;
#pragma unroll
        for (int k = 1; k < NCHUNK; ++k) {
            float v = cand_d[(size_t)k * Ns + i];
            bool c = v < best;
            best = c ? v : best;
            bk   = c ? k : bk;
        }
        int bidx = bk * CHUNK + (int)cand_j[(size_t)bk * Ns + i];

        // ---- student features (64 VGPRs, the only big live block)
        float4 f[D / 4];
        const float4* fr = reinterpret_cast<const float4*>(s_feat + (size_t)i * D);
#pragma unroll
        for (int k = 0; k < D / 4; ++k) f[k] = fr[k];

        // ---- gather matched teacher logits (6 x float4, 96 B aligned)
        float tt[TLP];
        {
            const float4* tr = reinterpret_cast<const float4*>(tlog + (size_t)bidx * TLP);
#pragma unroll
            for (int k = 0; k < TLP / 4; ++k) reinterpret_cast<float4*>(tt)[k] = tr[k];
        }
        float mt = tt[0];
#pragma unroll
        for (int c = 1; c < C; ++c) mt = fmaxf(mt, tt[c]);

        auto logit = [&](int c) -> float {
            float a = bsh[c];
            const float4* wr = reinterpret_cast<const float4*>(&ws[c * D]);
#pragma unroll
            for (int k = 0; k < D / 4; ++k) {
                float4 wv = wr[k];
                a = fmaf(f[k].x, wv.x, a);
                a = fmaf(f[k].y, wv.y, a);
                a = fmaf(f[k].z, wv.z, a);
                a = fmaf(f[k].w, wv.w, a);
            }
            return a;
        };

        // ---- pass A: student max only
        float m1 = logit(0);
#pragma unroll
        for (int c = 1; c < C; ++c) m1 = fmaxf(m1, logit(c));

        // ---- pass B: fused CE sums + expanded KL
        // kl_row = [sum_c u_c*0.5*((t_c-mt)-(l_c-m1))]/U + lse2 - log U
        int sg = segment[i];
        float sum1 = 0.f, sum2 = 0.f, U = 0.f, T = 0.f, lsg = 0.f;
#pragma unroll
        for (int c = 0; c < C; ++c) {
            float dlc = logit(c) - m1;
            sum1 += expf(dlc);
            sum2 += expf(0.5f * dlc);
            if (c == sg) lsg = dlc;
            float du = tt[c] - mt;
            float u = expf(0.5f * du);
            U += u;
            T = fmaf(u, 0.5f * (du - dlc), T);
        }
        seg_a += logf(sum1) - lsg;
        kl_a  += T / U + logf(sum2) - logf(U);
    }

    // ---- wave reduce (2 waves/block), one atomic pair per block
#pragma unroll
    for (int off = 32; off > 0; off >>= 1) {
        seg_a += __shfl_down(seg_a, off);
        kl_a  += __shfl_down(kl_a,  off);
    }
    int lane = threadIdx.x & 63, wv = threadIdx.x >> 6;
    if (lane == 0) { rs[wv] = seg_a; rk[wv] = kl_a; }
    __syncthreads();
    if (threadIdx.x == 0) {
        atomicAdd(&acc[0], rs[0] + rs[1]);
        atomicAdd(&acc[1], rk[0] + rk[1]);
        __threadfence();
        unsigned t = atomicAdd(ct, 1u);
        if (t == gridDim.x - 1) {
            float seg = atomicAdd(&acc[0], 0.f);   // coherent read
            float kl  = atomicAdd(&acc[1], 0.f);
            float seg_loss = seg / (float)Ns;
            float kl_loss  = KL_W_F * (kl / (float)Ns) * TEMP_F * TEMP_F;
            out[0] = seg_loss + kl_loss;
            out[1] = seg_loss;
            out[2] = kl_loss;
        }
    }
}

extern "C" void kernel_launch(void* const* d_in, const int* in_sizes, int n_in,
                              void* d_out, int out_size, void* d_ws, size_t ws_size,
                              hipStream_t stream)
{
    const float* s_feat  = (const float*)d_in[0];
    const float* t_feat  = (const float*)d_in[1];
    const float* s_coord = (const float*)d_in[2];
    const float* t_coord = (const float*)d_in[3];
    const float* seg_W   = (const float*)d_in[4];
    const float* seg_b   = (const float*)d_in[5];
    const float* seg_tW  = (const float*)d_in[6];
    const float* seg_tb  = (const float*)d_in[7];
    const int*   segment = (const int*)d_in[8];
    float* out = (float*)d_out;

    const int Ns = in_sizes[0] / D;
    const int Nt = in_sizes[1] / D;

    float* tlog   = (float*)d_ws;                                     // [Nt*TLP]
    float* cand_d = tlog + (size_t)Nt * TLP;                          // [NCHUNK*Ns]
    unsigned short* cand_j = (unsigned short*)(cand_d + (size_t)NCHUNK * Ns);
    float* acc    = (float*)(cand_j + (size_t)NCHUNK * Ns);           // [2]
    unsigned* ct  = (unsigned*)(acc + 2);

    const int subs     = (Ns + 256 * SPT - 1) / (256 * SPT);          // 16
    const int nn_total = subs * NCHUNK;                               // 512
    const int ntb      = (Nt + 255) / 256;                            // 64

    fat_kernel<<<nn_total + ntb, 256, 0, stream>>>(
        s_coord, t_coord, t_feat, seg_tW, seg_tb,
        cand_d, cand_j, tlog, acc, ct, Ns, Nt, nn_total);

    loss_kernel<<<128, 128, 0, stream>>>(
        s_feat, seg_W, seg_b, segment, tlog, cand_d, cand_j, acc, ct, out, Ns);
}

// Round 5
// 67.172 us; speedup vs baseline: 3.2455x; 1.9538x over previous
//
#include <hip/hip_runtime.h>
#include <math.h>

#define D 64
#define C 22
#define NCHUNK 32
#define CHUNK 512           // NCHUNK*CHUNK covers Nt=16384; INF-padded otherwise
#define SPT 4               // students per thread in nn role
#define TLP 24              // padded logit row (6 x float4)
#define TEMP_F 2.0f
#define KL_W_F 0.2f

// ---------------------------------------------------------------- logits role body
// Coalesced GEMV: one row of features per thread, weights in LDS.
// Proven lean (VGPR~64, no spill) in round-1 tlogits form.
__device__ __forceinline__ void logits_role(
        const float* __restrict__ feat, const float* __restrict__ W,
        const float* __restrict__ bias, float* __restrict__ olog,
        float* smem, int row0, int N)
{
    float* w = smem;                                   // C*D floats
    float* b = smem + C * D;
    for (int k = threadIdx.x; k < C * D; k += 256) w[k] = W[k];
    if (threadIdx.x < C) b[threadIdx.x] = bias[threadIdx.x];
    __syncthreads();

    int i = row0 + threadIdx.x;
    if (i >= N) return;

    float4 f[D / 4];
    const float4* fr = reinterpret_cast<const float4*>(feat + (size_t)i * D);
#pragma unroll
    for (int k = 0; k < D / 4; ++k) f[k] = fr[k];

    float* row = olog + (size_t)i * TLP;
#pragma unroll
    for (int c = 0; c < C; ++c) {
        float a = b[c];
        const float4* wr = reinterpret_cast<const float4*>(&w[c * D]);
#pragma unroll
        for (int k = 0; k < D / 4; ++k) {
            float4 wv = wr[k];
            a = fmaf(f[k].x, wv.x, a);
            a = fmaf(f[k].y, wv.y, a);
            a = fmaf(f[k].z, wv.z, a);
            a = fmaf(f[k].w, wv.w, a);
        }
        row[c] = a;
    }
}

// ================================================================ fat kernel
// role by blockIdx.x:  [0, nn_total)                -> 1-NN
//                      [nn_total, nn_total+ntb)     -> teacher logits
//                      [nn_total+ntb, +nsb)         -> student logits
__global__ void __launch_bounds__(256) fat_kernel(
        const float* __restrict__ sc,      // [Ns][3]
        const float* __restrict__ tc,      // [Nt][3]
        const float* __restrict__ t_feat,  // [Nt][D]
        const float* __restrict__ s_feat,  // [Ns][D]
        const float* __restrict__ Wt, const float* __restrict__ bt,
        const float* __restrict__ Ws, const float* __restrict__ bs_,
        float*  __restrict__ cand_d,       // [NCHUNK][Ns]  chunk-major
        unsigned short* __restrict__ cand_j,
        float*  __restrict__ tlog,         // [Nt][TLP]
        float*  __restrict__ slog,         // [Ns][TLP]
        float*  __restrict__ acc, unsigned* __restrict__ ct,
        int Ns, int Nt, int nn_total, int ntb)
{
    __shared__ __align__(16) float smem[CHUNK * 4];   // 8 KiB, role-dependent
    const int bx = blockIdx.x;

    if (bx == 0 && threadIdx.x == 0) { acc[0] = 0.f; acc[1] = 0.f; *ct = 0u; }

    if (bx < nn_total) {
        // ---------------- 1-NN role ----------------
        float4* tl = reinterpret_cast<float4*>(smem);
        const int chunk = bx & (NCHUNK - 1);
        const int sub   = bx >> 5;                     // log2(NCHUNK)
        const int base  = chunk * CHUNK;

        for (int j = threadIdx.x; j < CHUNK; j += 256) {
            int g = base + j;
            if (g < Nt) {
                float x = tc[(size_t)g * 3 + 0];
                float y = tc[(size_t)g * 3 + 1];
                float z = tc[(size_t)g * 3 + 2];
                tl[j] = make_float4(-2.f * x, -2.f * y, -2.f * z, x * x + y * y + z * z);
            } else {
                tl[j] = make_float4(0.f, 0.f, 0.f, INFINITY);
            }
        }
        __syncthreads();

        const int i0 = sub * (256 * SPT) + threadIdx.x;
        float sx[SPT], sy[SPT], sz[SPT];
#pragma unroll
        for (int s = 0; s < SPT; ++s) {
            int i = i0 + s * 256;
            sx[s] = 0.f; sy[s] = 0.f; sz[s] = 0.f;
            if (i < Ns) {
                sx[s] = sc[(size_t)i * 3 + 0];
                sy[s] = sc[(size_t)i * 3 + 1];
                sz[s] = sc[(size_t)i * 3 + 2];
            }
        }
        float best[SPT]; int bj[SPT];
#pragma unroll
        for (int s = 0; s < SPT; ++s) { best[s] = INFINITY; bj[s] = 0; }

#pragma unroll 8
        for (int j = 0; j < CHUNK; ++j) {
            float4 t = tl[j];
#pragma unroll
            for (int s = 0; s < SPT; ++s) {
                // |t|^2 - 2 s.t  (|s|^2 constant per student: same argmin)
                float v = fmaf(sx[s], t.x, fmaf(sy[s], t.y, fmaf(sz[s], t.z, t.w)));
                bool c = v < best[s];                  // strict <: first-min
                best[s] = c ? v : best[s];
                bj[s]   = c ? j : bj[s];
            }
        }
#pragma unroll
        for (int s = 0; s < SPT; ++s) {
            int i = i0 + s * 256;
            if (i < Ns) {
                cand_d[(size_t)chunk * Ns + i] = best[s];
                cand_j[(size_t)chunk * Ns + i] = (unsigned short)bj[s];
            }
        }
    } else if (bx < nn_total + ntb) {
        logits_role(t_feat, Wt, bt, tlog, smem, (bx - nn_total) * 256, Nt);
    } else {
        logits_role(s_feat, Ws, bs_, slog, smem, (bx - nn_total - ntb) * 256, Ns);
    }
}

// ================================================================ loss (+finalize)
// NO GEMV here: pure gather + 22-class scalar math. Live set ~70 VGPRs.
__global__ void __launch_bounds__(64) loss_kernel(
        const int*   __restrict__ segment,  // [Ns]
        const float* __restrict__ tlog,     // [Nt][TLP]
        const float* __restrict__ slog,     // [Ns][TLP]
        const float* __restrict__ cand_d,   // [NCHUNK][Ns]
        const unsigned short* __restrict__ cand_j,
        float* __restrict__ acc, unsigned* __restrict__ ct,
        float* __restrict__ out, int Ns)
{
    float seg_a = 0.f, kl_a = 0.f;

    for (int i = blockIdx.x * blockDim.x + threadIdx.x; i < Ns;
         i += gridDim.x * blockDim.x) {
        // ---- reduce chunk minima (k ascending, strict <: first occurrence)
        float best = cand_d[i];
        int bk = 0;
#pragma unroll
        for (int k = 1; k < NCHUNK; ++k) {
            float v = cand_d[(size_t)k * Ns + i];
            bool c = v < best;
            best = c ? v : best;
            bk   = c ? k : bk;
        }
        int bidx = bk * CHUNK + (int)cand_j[(size_t)bk * Ns + i];

        // ---- load both logit rows (6 x float4 each)
        float tt[TLP], ll[TLP];
        {
            const float4* tr = reinterpret_cast<const float4*>(tlog + (size_t)bidx * TLP);
            const float4* sr = reinterpret_cast<const float4*>(slog + (size_t)i * TLP);
#pragma unroll
            for (int k = 0; k < TLP / 4; ++k) {
                reinterpret_cast<float4*>(tt)[k] = tr[k];
                reinterpret_cast<float4*>(ll)[k] = sr[k];
            }
        }

        float m1 = ll[0], mt = tt[0];
#pragma unroll
        for (int c = 1; c < C; ++c) { m1 = fmaxf(m1, ll[c]); mt = fmaxf(mt, tt[c]); }

        // ---- fused CE sums + expanded KL
        // kl_row = [sum_c u_c*0.5*((t_c-mt)-(l_c-m1))]/U + lse2 - log U
        int sg = segment[i];
        float sum1 = 0.f, sum2 = 0.f, U = 0.f, T = 0.f, lsg = 0.f;
#pragma unroll
        for (int c = 0; c < C; ++c) {
            float dlc = ll[c] - m1;
            sum1 += expf(dlc);
            sum2 += expf(0.5f * dlc);
            if (c == sg) lsg = dlc;
            float du = tt[c] - mt;
            float u = expf(0.5f * du);
            U += u;
            T = fmaf(u, 0.5f * (du - dlc), T);
        }
        seg_a += logf(sum1) - lsg;
        kl_a  += T / U + logf(sum2) - logf(U);
    }

    // ---- single-wave shuffle reduce, one atomic pair per block
#pragma unroll
    for (int off = 32; off > 0; off >>= 1) {
        seg_a += __shfl_down(seg_a, off);
        kl_a  += __shfl_down(kl_a,  off);
    }
    if (threadIdx.x == 0) {
        atomicAdd(&acc[0], seg_a);
        atomicAdd(&acc[1], kl_a);
        __threadfence();
        unsigned t = atomicAdd(ct, 1u);
        if (t == gridDim.x - 1) {
            float seg = atomicAdd(&acc[0], 0.f);   // coherent read
            float kl  = atomicAdd(&acc[1], 0.f);
            float seg_loss = seg / (float)Ns;
            float kl_loss  = KL_W_F * (kl / (float)Ns) * TEMP_F * TEMP_F;
            out[0] = seg_loss + kl_loss;
            out[1] = seg_loss;
            out[2] = kl_loss;
        }
    }
}

extern "C" void kernel_launch(void* const* d_in, const int* in_sizes, int n_in,
                              void* d_out, int out_size, void* d_ws, size_t ws_size,
                              hipStream_t stream)
{
    const float* s_feat  = (const float*)d_in[0];
    const float* t_feat  = (const float*)d_in[1];
    const float* s_coord = (const float*)d_in[2];
    const float* t_coord = (const float*)d_in[3];
    const float* seg_W   = (const float*)d_in[4];
    const float* seg_b   = (const float*)d_in[5];
    const float* seg_tW  = (const float*)d_in[6];
    const float* seg_tb  = (const float*)d_in[7];
    const int*   segment = (const int*)d_in[8];
    float* out = (float*)d_out;

    const int Ns = in_sizes[0] / D;
    const int Nt = in_sizes[1] / D;

    float* tlog   = (float*)d_ws;                                     // [Nt*TLP]
    float* slog   = tlog + (size_t)Nt * TLP;                          // [Ns*TLP]
    float* cand_d = slog + (size_t)Ns * TLP;                          // [NCHUNK*Ns]
    unsigned short* cand_j = (unsigned short*)(cand_d + (size_t)NCHUNK * Ns);
    float* acc    = (float*)(cand_j + (size_t)NCHUNK * Ns);           // [2]
    unsigned* ct  = (unsigned*)(acc + 2);

    const int subs     = (Ns + 256 * SPT - 1) / (256 * SPT);          // 16
    const int nn_total = subs * NCHUNK;                               // 512
    const int ntb      = (Nt + 255) / 256;                            // 64
    const int nsb      = (Ns + 255) / 256;                            // 64

    fat_kernel<<<nn_total + ntb + nsb, 256, 0, stream>>>(
        s_coord, t_coord, t_feat, s_feat, seg_tW, seg_tb, seg_W, seg_b,
        cand_d, cand_j, tlog, slog, acc, ct, Ns, Nt, nn_total, ntb);

    loss_kernel<<<256, 64, 0, stream>>>(
        segment, tlog, slog, cand_d, cand_j, acc, ct, out, Ns);
}